// Round 8
// baseline (1635.369 us; speedup 1.0000x reference)
//
#include <hip/hip_runtime.h>
#include <hip/hip_bf16.h>
#include <math.h>

typedef __hip_bfloat16 bf16;
typedef __bf16 bf16x8 __attribute__((ext_vector_type(8)));
typedef float f32x4 __attribute__((ext_vector_type(4)));

#define HH 56
#define WW 56
#define WSZ 7
#define SSH 3
#define NHEAD 12
#define CDIM 384
#define BBATCH 32
#define NTOK 49
#define NWIN 64
#define HIDD 1536
#define HD 32
#define NWTOT (BBATCH*NWIN)       /* 2048 windows */
#define MROWS (NWTOT*NTOK)        /* 100352 rows */
#define MHALF (MROWS/2)           /* 50176 */
#define LTOT (HH*WW)
#define EPSLN 1e-5f
#define QSCALE 0.17677669529663687f
#define NEGBIG -1e30f

enum { M_QK = 0, M_V = 1, M_FC1 = 2 };

__device__ __forceinline__ void gload16(const void* g, void* l) {
    __builtin_amdgcn_global_load_lds(
        (const __attribute__((address_space(1))) void*)g,
        (__attribute__((address_space(3))) void*)l, 16, 0, 0);
}

__device__ __forceinline__ unsigned short bfbits(float v) {
    bf16 b = __float2bfloat16(v);
    return *reinterpret_cast<unsigned short*>(&b);
}

__device__ __forceinline__ int xcd_swz(int orig, int nwg) {
    const int q = nwg >> 3, r = nwg & 7;
    const int xcd = orig & 7, loc = orig >> 3;
    return (xcd < r ? xcd * (q + 1) : r * (q + 1) + (xcd - r) * q) + loc;
}

// ---------------------------------------------------------------------------
__global__ __launch_bounds__(256) void cvt_k(const float* __restrict__ src,
                                             bf16* __restrict__ dst, int n) {
    int i = blockIdx.x * 256 + threadIdx.x;
    if (i < n) dst[i] = __float2bfloat16(src[i]);
}

// bias+mask table: tbl[wi][h][n][m(pad64)] ; m>=49 -> -1e30 (softmax automask)
__global__ __launch_bounds__(256)
void tbl_k(const float* __restrict__ rpb, const int* __restrict__ relidx,
           const float* __restrict__ amask, float* __restrict__ tbl) {
    int idx = blockIdx.x * 256 + threadIdx.x;   // 64*12*64*64
    int m = idx & 63, n = (idx >> 6) & 63;
    int h = (idx >> 12) % NHEAD, wi = idx / (64 * 64 * NHEAD);
    float v;
    if (m >= NTOK) v = NEGBIG;
    else if (n >= NTOK) v = 0.f;
    else v = rpb[relidx[n * NTOK + m] * NHEAD + h] + amask[((long)wi * NTOK + n) * NTOK + m];
    tbl[idx] = v;
}

// x [B][L][C] fp32 -> xw [MROWS][C] bf16 with cyclic shift + window partition
__global__ __launch_bounds__(256) void gather_k(const float* __restrict__ x,
                                                bf16* __restrict__ xw) {
    int idx = blockIdx.x * 256 + threadIdx.x;
    int rr = idx / 96, c4 = (idx % 96) * 4;
    int w = rr / 49, ti = rr % 49;
    int b = w >> 6, wi = w & 63;
    int hy = (wi >> 3) * 7 + ti / 7;
    int hx = (wi & 7) * 7 + ti % 7;
    int sh = hy + SSH; if (sh >= HH) sh -= HH;
    int sw = hx + SSH; if (sw >= WW) sw -= WW;
    float4 v = *(const float4*)&x[((long)b * LTOT + sh * WW + sw) * CDIM + c4];
    bf16* o = &xw[(long)rr * CDIM + c4];
    o[0] = __float2bfloat16(v.x); o[1] = __float2bfloat16(v.y);
    o[2] = __float2bfloat16(v.z); o[3] = __float2bfloat16(v.w);
}

// ---------------------------------------------------------------------------
// MFMA GEMM. 128x128 tile, BK=64, 4 waves. A: dbuf LDS (T2 swizzle, 32 KB).
// B (weights, L2-resident): fragments loaded DIRECTLY from global per K-step.
// 2-phase sync; occupancy 4 blk/CU (VGPR<=128). XCD-chunked m-major dispatch.
// ---------------------------------------------------------------------------
template<int MODE, int KDIM, int NTN>
__global__ __launch_bounds__(256, 4)
void mgemm_k(const bf16* __restrict__ A, const bf16* __restrict__ Wt,
             const float* __restrict__ bias, void* __restrict__ Outp)
{
    constexpr bool SWAP = (MODE != M_V);
    __shared__ bf16 As[2][128 * 64];
    const int tid = threadIdx.x;
    const int wid = tid >> 6, lane = tid & 63;

    const int gid = xcd_swz(blockIdx.x, gridDim.x);
    const int m0 = (gid / NTN) * 128;
    const int n0 = (gid % NTN) * 128;

    const int srow = lane >> 3, sseg = lane & 7;
    const int swseg = sseg ^ (srow & 7);
    const bf16* Ag = A + (long)(m0 + wid * 32 + srow) * KDIM + swseg * 8;

    const int wr = (wid >> 1) * 64, wc = (wid & 1) * 64;
    const int l15 = lane & 15, g4 = lane >> 4;
    const bf16* Wb = Wt + (long)(n0 + wc + l15) * KDIM + g4 * 8;  // per-lane B row

    f32x4 acc[4][4] = {};

    auto STAGE = [&](int b, int t) {
#pragma unroll
        for (int i = 0; i < 4; ++i)
            gload16(Ag + (long)(i * 8) * KDIM + t * 64, &As[b][(wid * 32 + i * 8) * 64]);
    };

    const int nt = KDIM / 64;
    STAGE(0, 0);
    __syncthreads();
    int buf = 0;
    for (int t = 0; t < nt; ++t) {
        if (t + 1 < nt) STAGE(buf ^ 1, t + 1);
#pragma unroll
        for (int kk = 0; kk < 2; ++kk) {
            bf16x8 bfr[4], af[4];
#pragma unroll
            for (int i = 0; i < 4; ++i)
                bfr[i] = *(const bf16x8*)&Wb[(long)(i * 16) * KDIM + t * 64 + kk * 32];
#pragma unroll
            for (int i = 0; i < 4; ++i) {
                const int ra = wr + i * 16 + l15;
                const int sa = (4 * kk + g4) ^ (ra & 7);
                af[i] = *(const bf16x8*)&As[buf][ra * 64 + sa * 8];
            }
#pragma unroll
            for (int mi = 0; mi < 4; ++mi)
#pragma unroll
                for (int ni = 0; ni < 4; ++ni) {
                    if (SWAP)
                        acc[ni][mi] = __builtin_amdgcn_mfma_f32_16x16x32_bf16(
                            bfr[ni], af[mi], acc[ni][mi], 0, 0, 0);
                    else
                        acc[mi][ni] = __builtin_amdgcn_mfma_f32_16x16x32_bf16(
                            af[mi], bfr[ni], acc[mi][ni], 0, 0, 0);
                }
        }
        __syncthreads();
        buf ^= 1;
    }

    // ---------------- epilogue ----------------
    if (MODE == M_V) {
        // acc[mi][ni][j]: m = m0+wr+mi*16+g4*4+j (ti dir), n = n0+wc+ni*16+l15
#pragma unroll
        for (int mi = 0; mi < 4; ++mi) {
            const int mb = m0 + wr + mi * 16 + g4 * 4;
            const int wv_ = mb / 49, ti0 = mb - wv_ * 49;
#pragma unroll
            for (int ni = 0; ni < 4; ++ni) {
                const int n = n0 + wc + ni * 16 + l15;     // h*32+d
                const int h = n >> 5, d = n & 31;
                const float bn = bias[n];
                float v4[4];
#pragma unroll
                for (int j = 0; j < 4; ++j) v4[j] = acc[mi][ni][j] + bn;
                if (ti0 <= 45) {
                    ushort4 u = { bfbits(v4[0]), bfbits(v4[1]), bfbits(v4[2]), bfbits(v4[3]) };
                    *(ushort4*)&((bf16*)Outp)[(((long)wv_ * NHEAD + h) * HD + d) * 64 + ti0] = u;
                } else {
#pragma unroll
                    for (int j = 0; j < 4; ++j) {
                        const int m = mb + j;
                        const int w2 = m / 49, ti = m - w2 * 49;
                        ((bf16*)Outp)[(((long)w2 * NHEAD + h) * HD + d) * 64 + ti]
                            = __float2bfloat16(v4[j]);
                    }
                }
            }
        }
    } else {
        // acc[ni][mi][j]: n = n0+wc+ni*16+g4*4+j, m = m0+wr+mi*16+l15
        long rowbase[4];
        int wq_[4], ti_[4];
#pragma unroll
        for (int mi = 0; mi < 4; ++mi) {
            const int m = m0 + wr + mi * 16 + l15;
            if (MODE == M_QK) { wq_[mi] = m / 49; ti_[mi] = m - wq_[mi] * 49; }
            else rowbase[mi] = (long)m * HIDD;
        }
#pragma unroll
        for (int ni = 0; ni < 4; ++ni) {
            const int nb = n0 + wc + ni * 16 + g4 * 4;
            const float4 bn = *(const float4*)&bias[nb];
            const float bb[4] = { bn.x, bn.y, bn.z, bn.w };
#pragma unroll
            for (int mi = 0; mi < 4; ++mi) {
                float v4[4];
#pragma unroll
                for (int j = 0; j < 4; ++j) v4[j] = acc[ni][mi][j] + bb[j];
                if (MODE == M_FC1) {
#pragma unroll
                    for (int j = 0; j < 4; ++j)
                        v4[j] = 0.5f * v4[j] * (1.0f + erff(v4[j] * 0.70710678118654752f));
                } else {
                    if (nb < CDIM) {
#pragma unroll
                        for (int j = 0; j < 4; ++j) v4[j] *= QSCALE;
                    }
                }
                ushort4 u = { bfbits(v4[0]), bfbits(v4[1]), bfbits(v4[2]), bfbits(v4[3]) };
                if (MODE == M_QK) {
                    const int which = nb >= CDIM;
                    const int hb = (nb - which * CDIM) >> 5, d0 = nb & 31;
                    *(ushort4*)&((bf16*)Outp)[
                        ((((long)wq_[mi] * 2 + which) * NHEAD + hb) * NTOK + ti_[mi]) * HD + d0] = u;
                } else {
                    *(ushort4*)&((bf16*)Outp)[rowbase[mi] + nb] = u;
                }
            }
        }
    }
}

// ---------------------------------------------------------------------------
// Fused GEMM(128 x 384 x K) + row-LayerNorm + residual-add.
// 1024 thr = 16 waves (4M x 4N), wave tile 32x96 (2mi x 6ni, SWAP C^T frags).
// A: dbuf LDS (32 KB, T2 swizzle); B (weights) direct-from-global (L2).
// outp[t] = base[t] + LN(A@W^T + bias)[t]*g + b  (fp32 float4 stores);
// SCATTER: t = window-reverse(m), also writes bf16 copy.
// ---------------------------------------------------------------------------
template<int KDIM, bool SCATTER>
__global__ __launch_bounds__(1024, 4)
void gemm_ln_k(const bf16* __restrict__ A, const bf16* __restrict__ Wt,
               const float* __restrict__ bias, const float* __restrict__ base,
               const float* __restrict__ lng, const float* __restrict__ lnb,
               float* __restrict__ outp, bf16* __restrict__ outb)
{
    __shared__ bf16 As[2][128 * 64];     // 32 KB
    __shared__ float lnp[1024];          // 4 KB: [sum|sq][4 wn][128 rows]
    const int tid = threadIdx.x;
    const int wid = tid >> 6, lane = tid & 63;

    const int m0 = xcd_swz(blockIdx.x, gridDim.x) * 128;

    const int srow = lane >> 3, sseg = lane & 7;
    const int swseg = sseg ^ (srow & 7);
    const bf16* Ag = A + (long)(m0 + wid * 8 + srow) * KDIM + swseg * 8;

    const int wm = wid >> 2, wn = wid & 3;
    const int wr = wm * 32, wc = wn * 96;
    const int l15 = lane & 15, g4 = lane >> 4;
    const bf16* Wb = Wt + (long)(wc + l15) * KDIM + g4 * 8;

    f32x4 acc[6][2] = {};   // [ni][mi]: n = wc+ni*16+g4*4+j, m = wr+mi*16+l15

    auto STAGE = [&](int b, int t) {
        gload16(Ag + t * 64, &As[b][(wid * 8) * 64]);
    };

    const int nt = KDIM / 64;
    STAGE(0, 0);
    __syncthreads();
    int buf = 0;
    for (int t = 0; t < nt; ++t) {
        if (t + 1 < nt) STAGE(buf ^ 1, t + 1);
#pragma unroll
        for (int kk = 0; kk < 2; ++kk) {
            bf16x8 bfr[6], af[2];
#pragma unroll
            for (int i = 0; i < 6; ++i)
                bfr[i] = *(const bf16x8*)&Wb[(long)(i * 16) * KDIM + t * 64 + kk * 32];
#pragma unroll
            for (int i = 0; i < 2; ++i) {
                const int ra = wr + i * 16 + l15;
                const int sa = (4 * kk + g4) ^ (ra & 7);
                af[i] = *(const bf16x8*)&As[buf][ra * 64 + sa * 8];
            }
#pragma unroll
            for (int ni = 0; ni < 6; ++ni)
#pragma unroll
                for (int mi = 0; mi < 2; ++mi)
                    acc[ni][mi] = __builtin_amdgcn_mfma_f32_16x16x32_bf16(
                        bfr[ni], af[mi], acc[ni][mi], 0, 0, 0);
        }
        __syncthreads();
        buf ^= 1;
    }

    // ---- epilogue: bias add, row partial sums, cross-wave LN reduce ----
    float psum[2] = {}, psq[2] = {};
#pragma unroll
    for (int ni = 0; ni < 6; ++ni) {
        const int nb = wc + ni * 16 + g4 * 4;
        const float4 bn = *(const float4*)&bias[nb];
        const float bb[4] = { bn.x, bn.y, bn.z, bn.w };
#pragma unroll
        for (int mi = 0; mi < 2; ++mi)
#pragma unroll
            for (int j = 0; j < 4; ++j) {
                float v = acc[ni][mi][j] + bb[j];
                acc[ni][mi][j] = v;
                psum[mi] += v; psq[mi] += v * v;
            }
    }
#pragma unroll
    for (int mi = 0; mi < 2; ++mi) {
        psum[mi] += __shfl_xor(psum[mi], 16); psum[mi] += __shfl_xor(psum[mi], 32);
        psq[mi]  += __shfl_xor(psq[mi], 16);  psq[mi]  += __shfl_xor(psq[mi], 32);
    }
    if (g4 == 0) {
#pragma unroll
        for (int mi = 0; mi < 2; ++mi) {
            const int rl = wr + mi * 16 + l15;
            lnp[wn * 128 + rl] = psum[mi];
            lnp[512 + wn * 128 + rl] = psq[mi];
        }
    }
    __syncthreads();

#pragma unroll
    for (int mi = 0; mi < 2; ++mi) {
        const int rl = wr + mi * 16 + l15;
        const float s  = lnp[rl] + lnp[128 + rl] + lnp[256 + rl] + lnp[384 + rl];
        const float sq = lnp[512 + rl] + lnp[640 + rl] + lnp[768 + rl] + lnp[896 + rl];
        const float mean = s * (1.f / 384.f);
        const float rstd = rsqrtf(sq * (1.f / 384.f) - mean * mean + EPSLN);

        const int m = m0 + rl;
        long tok;
        if (SCATTER) {
            int w = m / 49, ti = m - w * 49;
            int b = w >> 6, wi = w & 63;
            int hy = (wi >> 3) * 7 + ti / 7;
            int hx = (wi & 7) * 7 + ti % 7;
            int dh = hy + SSH; if (dh >= HH) dh -= HH;
            int dw = hx + SSH; if (dw >= WW) dw -= WW;
            tok = (long)b * LTOT + dh * WW + dw;
        } else {
            tok = m;
        }
#pragma unroll
        for (int ni = 0; ni < 6; ++ni) {
            const int c = wc + ni * 16 + g4 * 4;
            const float4 gv = *(const float4*)&lng[c];
            const float4 bv = *(const float4*)&lnb[c];
            const float4 xv = *(const float4*)&base[tok * CDIM + c];
            float4 r;
            r.x = xv.x + (acc[ni][mi][0] - mean) * rstd * gv.x + bv.x;
            r.y = xv.y + (acc[ni][mi][1] - mean) * rstd * gv.y + bv.y;
            r.z = xv.z + (acc[ni][mi][2] - mean) * rstd * gv.z + bv.z;
            r.w = xv.w + (acc[ni][mi][3] - mean) * rstd * gv.w + bv.w;
            *(float4*)&outp[tok * CDIM + c] = r;
            if (SCATTER) {
                ushort4 u = { bfbits(r.x), bfbits(r.y), bfbits(r.z), bfbits(r.w) };
                *(ushort4*)&outb[tok * CDIM + c] = u;
            }
        }
    }
}

// ---------------------------------------------------------------------------
// MFMA attention: 4 waves/block, each wave = one (window, head). Unchanged.
// ---------------------------------------------------------------------------
__global__ __launch_bounds__(256)
void mattn_k(const bf16* __restrict__ qk, const bf16* __restrict__ vT,
             const float* __restrict__ tbl, bf16* __restrict__ attn_out)
{
    __shared__ bf16 Plds[4][64 * 72];
    const int tid = threadIdx.x, wid = tid >> 6, lane = tid & 63;
    const int t = blockIdx.x * 4 + wid;
    const int w = t / NHEAD, h = t % NHEAD, wi = w & 63;
    const int l15 = lane & 15, g = lane >> 4;
    const bf16* qb = qk + ((long)(w * 2 + 0) * NHEAD + h) * (NTOK * HD);
    const bf16* kb = qk + ((long)(w * 2 + 1) * NHEAD + h) * (NTOK * HD);
    const bf16* vt = vT + ((long)w * NHEAD + h) * (HD * 64);
    const float* Tb = tbl + (long)(wi * NHEAD + h) * 64 * 64;
    char* Pw = (char*)&Plds[wid][0];

    bf16x8 kf[4], qf[4];
#pragma unroll
    for (int i = 0; i < 4; ++i) {
        kf[i] = *(const bf16x8*)&kb[(16 * i + l15) * HD + 8 * g];
        qf[i] = *(const bf16x8*)&qb[(16 * i + l15) * HD + 8 * g];
    }
    f32x4 s[4][4] = {};
#pragma unroll
    for (int mi = 0; mi < 4; ++mi)
#pragma unroll
        for (int ni = 0; ni < 4; ++ni)
            s[mi][ni] = __builtin_amdgcn_mfma_f32_16x16x32_bf16(
                kf[mi], qf[ni], s[mi][ni], 0, 0, 0);

#pragma unroll
    for (int ni = 0; ni < 4; ++ni) {
        const int n = 16 * ni + l15;
#pragma unroll
        for (int mi = 0; mi < 4; ++mi) {
            float4 tv = *(const float4*)&Tb[(long)n * 64 + 16 * mi + 4 * g];
            s[mi][ni][0] += tv.x; s[mi][ni][1] += tv.y;
            s[mi][ni][2] += tv.z; s[mi][ni][3] += tv.w;
        }
        float mx = NEGBIG;
#pragma unroll
        for (int mi = 0; mi < 4; ++mi)
#pragma unroll
            for (int j = 0; j < 4; ++j) mx = fmaxf(mx, s[mi][ni][j]);
        mx = fmaxf(mx, __shfl_xor(mx, 16));
        mx = fmaxf(mx, __shfl_xor(mx, 32));
        float sum = 0.f;
#pragma unroll
        for (int mi = 0; mi < 4; ++mi)
#pragma unroll
            for (int j = 0; j < 4; ++j) {
                float e = expf(s[mi][ni][j] - mx);
                s[mi][ni][j] = e; sum += e;
            }
        sum += __shfl_xor(sum, 16);
        sum += __shfl_xor(sum, 32);
        const float r = 1.0f / sum;
#pragma unroll
        for (int mi = 0; mi < 4; ++mi) {
            ushort4 u;
            u.x = bfbits(s[mi][ni][0] * r);
            u.y = bfbits(s[mi][ni][1] * r);
            u.z = bfbits(s[mi][ni][2] * r);
            u.w = bfbits(s[mi][ni][3] * r);
            *(ushort4*)(Pw + (long)n * 144 + (16 * mi + 4 * g) * 2) = u;
        }
    }

    f32x4 o[4][2] = {};
#pragma unroll
    for (int kk = 0; kk < 2; ++kk) {
        bf16x8 vf[2];
        vf[0] = *(const bf16x8*)&vt[(long)(l15) * 64 + 32 * kk + 8 * g];
        vf[1] = *(const bf16x8*)&vt[(long)(16 + l15) * 64 + 32 * kk + 8 * g];
#pragma unroll
        for (int rt = 0; rt < 4; ++rt) {
            bf16x8 pf = *(const bf16x8*)(Pw + (long)(16 * rt + l15) * 144 + (32 * kk + 8 * g) * 2);
            o[rt][0] = __builtin_amdgcn_mfma_f32_16x16x32_bf16(pf, vf[0], o[rt][0], 0, 0, 0);
            o[rt][1] = __builtin_amdgcn_mfma_f32_16x16x32_bf16(pf, vf[1], o[rt][1], 0, 0, 0);
        }
    }

#pragma unroll
    for (int rt = 0; rt < 4; ++rt)
#pragma unroll
        for (int dt = 0; dt < 2; ++dt)
#pragma unroll
            for (int j = 0; j < 4; ++j) {
                int n = 16 * rt + 4 * g + j;
                if (n < NTOK)
                    attn_out[((long)w * NTOK + n) * CDIM + h * HD + 16 * dt + l15]
                        = __float2bfloat16(o[rt][dt][j]);
            }
}

extern "C" void kernel_launch(void* const* d_in, const int* in_sizes, int n_in,
                              void* d_out, int out_size, void* d_ws, size_t ws_size,
                              hipStream_t stream)
{
    const float* x      = (const float*)d_in[0];
    const float* qkv_w  = (const float*)d_in[1];
    const float* qkv_b  = (const float*)d_in[2];
    const float* proj_w = (const float*)d_in[3];
    const float* proj_b = (const float*)d_in[4];
    const float* rpb    = (const float*)d_in[5];
    const float* ln1_g  = (const float*)d_in[6];
    const float* ln1_b  = (const float*)d_in[7];
    const float* fc1_w  = (const float*)d_in[8];
    const float* fc1_b  = (const float*)d_in[9];
    const float* fc2_w  = (const float*)d_in[10];
    const float* fc2_b  = (const float*)d_in[11];
    const float* ln2_g  = (const float*)d_in[12];
    const float* ln2_b  = (const float*)d_in[13];
    const float* amask  = (const float*)d_in[14];
    const int*   relidx = (const int*)d_in[15];
    float* out = (float*)d_out;
    char*  ws  = (char*)d_ws;

    // workspace layout (peak 347,996,160 B; proven available)
    bf16*  wq   = (bf16*) (ws + 0L);            //   884,736
    bf16*  wp   = (bf16*) (ws + 884736L);       //   294,912
    bf16*  w1   = (bf16*) (ws + 1179648L);      // 1,179,648
    bf16*  w2   = (bf16*) (ws + 2359296L);      // 1,179,648
    float* tbl  = (float*)(ws + 3538944L);      // 12,582,912 (dead after mattn)
    bf16*  xw   = (bf16*) (ws + 16121856L);     // 77,070,336 (dead after QK/V)
    bf16*  qkb  = (bf16*) (ws + 93192192L);     // 154,140,672 (dead after mattn)
    bf16*  vTb  = (bf16*) (ws + 247332864L);    // 100,663,296 (dead after mattn)
    bf16*  attn_o = (bf16*)(ws + 16121856L);    // reuses xw (dead after proj_ln)
    bf16*  x1b  = (bf16*) (ws + 93192192L);     // reuses qkb (written by proj_ln)
    bf16*  H1   = (bf16*) (ws + 170262528L);    // 154,140,672 per FFN half

    dim3 b256(256), b1024(1024);

    cvt_k<<<dim3((3*CDIM*CDIM + 255)/256), b256, 0, stream>>>(qkv_w, wq, 3*CDIM*CDIM);
    cvt_k<<<dim3((CDIM*CDIM + 255)/256), b256, 0, stream>>>(proj_w, wp, CDIM*CDIM);
    cvt_k<<<dim3((HIDD*CDIM + 255)/256), b256, 0, stream>>>(fc1_w, w1, HIDD*CDIM);
    cvt_k<<<dim3((CDIM*HIDD + 255)/256), b256, 0, stream>>>(fc2_w, w2, CDIM*HIDD);
    tbl_k<<<dim3(64*12*64*64/256), b256, 0, stream>>>(rpb, relidx, amask, tbl);
    gather_k<<<dim3(MROWS * 96 / 256), b256, 0, stream>>>(x, xw);

    // 1a. Q,K projection   grid = 784*6
    mgemm_k<M_QK, CDIM, 6><<<dim3((MROWS/128)*6), b256, 0, stream>>>(
        xw, wq, qkv_b, (void*)qkb);
    // 1b. V projection -> transposed [w][h][d][64]  grid = 784*3
    mgemm_k<M_V, CDIM, 3><<<dim3((MROWS/128)*3), b256, 0, stream>>>(
        xw, wq + (long)2*CDIM*CDIM, qkv_b + 2*CDIM, (void*)vTb);

    // 2. MFMA windowed attention
    mattn_k<<<dim3(NWTOT * NHEAD / 4), b256, 0, stream>>>(qkb, vTb, tbl, attn_o);

    // 3. fused PROJ + LN1: out = x + LN(attn@Wp+b), + bf16 copy x1b
    gemm_ln_k<CDIM, true><<<dim3(MROWS/128), b1024, 0, stream>>>(
        attn_o, wp, proj_b, x, ln1_g, ln1_b, out, x1b);

    // 4/5. FFN in two M-halves; FC2 fused with LN2 (in-place on d_out)
    for (int c = 0; c < 2; ++c) {
        const long off = (long)c * MHALF * CDIM;
        mgemm_k<M_FC1, CDIM, 12><<<dim3((MHALF/128)*12), b256, 0, stream>>>(
            x1b + off, w1, fc1_b, (void*)H1);
        gemm_ln_k<HIDD, false><<<dim3(MHALF/128), b1024, 0, stream>>>(
            H1, w2, fc2_b, out + off, ln2_g, ln2_b, out + off, nullptr);
    }
}

// Round 9
// 944.053 us; speedup vs baseline: 1.7323x; 1.7323x over previous
//
#include <hip/hip_runtime.h>
#include <hip/hip_bf16.h>
#include <math.h>

typedef __hip_bfloat16 bf16;
typedef __bf16 bf16x8 __attribute__((ext_vector_type(8)));
typedef float f32x4 __attribute__((ext_vector_type(4)));

#define HH 56
#define WW 56
#define WSZ 7
#define SSH 3
#define NHEAD 12
#define CDIM 384
#define BBATCH 32
#define NTOK 49
#define NWIN 64
#define HIDD 1536
#define HD 32
#define NWTOT (BBATCH*NWIN)       /* 2048 windows */
#define MROWS (NWTOT*NTOK)        /* 100352 rows */
#define MHALF (MROWS/2)           /* 50176 rows = 16 batches */
#define LTOT (HH*WW)
#define EPSLN 1e-5f
#define QSCALE 0.17677669529663687f
#define NEGBIG -1e30f

enum { M_QK = 0, M_V = 1, M_FC1 = 2, M_ROW = 3 };

__device__ __forceinline__ void gload16(const void* g, void* l) {
    __builtin_amdgcn_global_load_lds(
        (const __attribute__((address_space(1))) void*)g,
        (__attribute__((address_space(3))) void*)l, 16, 0, 0);
}

__device__ __forceinline__ unsigned short bfbits(float v) {
    bf16 b = __float2bfloat16(v);
    return *reinterpret_cast<unsigned short*>(&b);
}

__device__ __forceinline__ int xcd_swz(int orig, int nwg) {
    const int q = nwg >> 3, r = nwg & 7;
    const int xcd = orig & 7, loc = orig >> 3;
    return (xcd < r ? xcd * (q + 1) : r * (q + 1) + (xcd - r) * q) + loc;
}

// ---------------------------------------------------------------------------
__global__ __launch_bounds__(256) void cvt_k(const float* __restrict__ src,
                                             bf16* __restrict__ dst, int n) {
    int i = blockIdx.x * 256 + threadIdx.x;
    if (i < n) dst[i] = __float2bfloat16(src[i]);
}

// bias+mask table: tbl[wi][h][n][m(pad64)] ; m>=49 -> -1e30 (softmax automask)
__global__ __launch_bounds__(256)
void tbl_k(const float* __restrict__ rpb, const int* __restrict__ relidx,
           const float* __restrict__ amask, float* __restrict__ tbl) {
    int idx = blockIdx.x * 256 + threadIdx.x;   // 64*12*64*64
    int m = idx & 63, n = (idx >> 6) & 63;
    int h = (idx >> 12) % NHEAD, wi = idx / (64 * 64 * NHEAD);
    float v;
    if (m >= NTOK) v = NEGBIG;
    else if (n >= NTOK) v = 0.f;
    else v = rpb[relidx[n * NTOK + m] * NHEAD + h] + amask[((long)wi * NTOK + n) * NTOK + m];
    tbl[idx] = v;
}

// x fp32 -> xw_h [MHALF][C] bf16, cyclic shift + window partition, half rbase
__global__ __launch_bounds__(256) void gather_k(const float* __restrict__ x,
                                                bf16* __restrict__ xw, int rbase) {
    int idx = blockIdx.x * 256 + threadIdx.x;
    int rr_l = idx / 96, c4 = (idx % 96) * 4;
    int rr = rbase + rr_l;
    int w = rr / 49, ti = rr % 49;
    int b = w >> 6, wi = w & 63;
    int hy = (wi >> 3) * 7 + ti / 7;
    int hx = (wi & 7) * 7 + ti % 7;
    int sh = hy + SSH; if (sh >= HH) sh -= HH;
    int sw = hx + SSH; if (sw >= WW) sw -= WW;
    float4 v = *(const float4*)&x[((long)b * LTOT + sh * WW + sw) * CDIM + c4];
    ushort4 u = { bfbits(v.x), bfbits(v.y), bfbits(v.z), bfbits(v.w) };
    *(ushort4*)&xw[(long)rr_l * CDIM + c4] = u;
}

// ---------------------------------------------------------------------------
// MFMA GEMM. 128x128 tile, BK=32, 4 waves, LDS 32 KB (A+B dbuf) -> 4 blk/CU.
// Counted-vmcnt pipeline (R5-verified shape, 4 loads/wave/tile), swizzle
// seg ^= (row>>1)&3 both sides. SWAP modes (all but M_V): C^T frags.
// ---------------------------------------------------------------------------
template<int MODE, int KDIM, int NTN>
__global__ __launch_bounds__(256, 4)
void mgemm_k(const bf16* __restrict__ A, const bf16* __restrict__ Wt,
             const float* __restrict__ bias, void* __restrict__ Outp)
{
    constexpr bool SWAP = (MODE != M_V);
    __shared__ bf16 As[2][128 * 32];
    __shared__ bf16 Bs[2][128 * 32];
    const int tid = threadIdx.x;
    const int wid = tid >> 6, lane = tid & 63;

    const int gid = xcd_swz(blockIdx.x, gridDim.x);
    const int m0 = (gid / NTN) * 128;
    const int n0 = (gid % NTN) * 128;

    // staging: wave covers rows [wid*32,+32), 2 issues of 16 rows each side.
    // lane -> (row-in-16 = lane>>2, seg = lane&3); source seg pre-swizzled.
    const int strow = lane >> 2, stseg = lane & 3;
    const int swseg = stseg ^ ((strow >> 1) & 3);
    const bf16* Ag = A + (long)(m0 + wid * 32 + strow) * KDIM + swseg * 8;
    const bf16* Wg = Wt + (long)(n0 + wid * 32 + strow) * KDIM + swseg * 8;

    const int wr = (wid >> 1) * 64, wc = (wid & 1) * 64;
    const int l15 = lane & 15, g4 = lane >> 4;
    const int sa = g4 ^ ((l15 >> 1) & 3);   // read seg (row bits 1..2 = l15's)

    f32x4 acc[4][4] = {};

    auto STAGE = [&](int b, int t) {
#pragma unroll
        for (int i = 0; i < 2; ++i)
            gload16(Ag + (long)(i * 16) * KDIM + t * 32, &As[b][(wid * 32 + i * 16) * 32]);
#pragma unroll
        for (int i = 0; i < 2; ++i)
            gload16(Wg + (long)(i * 16) * KDIM + t * 32, &Bs[b][(wid * 32 + i * 16) * 32]);
    };

    const int nt = KDIM / 32;
    STAGE(0, 0);
    STAGE(1, 1);
    asm volatile("s_waitcnt vmcnt(4)" ::: "memory");   // tile0's 4 landed
    __builtin_amdgcn_s_barrier();

    int buf = 0;
    for (int t = 0; t < nt; ++t) {
        bf16x8 af[4], bfr[4];
#pragma unroll
        for (int i = 0; i < 4; ++i) {
            af[i]  = *(const bf16x8*)&As[buf][(wr + i * 16 + l15) * 32 + sa * 8];
            bfr[i] = *(const bf16x8*)&Bs[buf][(wc + i * 16 + l15) * 32 + sa * 8];
        }
        __builtin_amdgcn_sched_barrier(0);
        asm volatile("s_waitcnt lgkmcnt(0)" ::: "memory");
        __builtin_amdgcn_sched_barrier(0);
        __builtin_amdgcn_s_barrier();        // all waves done reading buf
        if (t + 2 < nt) STAGE(buf, t + 2);   // refill just-freed buffer
#pragma unroll
        for (int mi = 0; mi < 4; ++mi)
#pragma unroll
            for (int ni = 0; ni < 4; ++ni) {
                if (SWAP)
                    acc[ni][mi] = __builtin_amdgcn_mfma_f32_16x16x32_bf16(
                        bfr[ni], af[mi], acc[ni][mi], 0, 0, 0);
                else
                    acc[mi][ni] = __builtin_amdgcn_mfma_f32_16x16x32_bf16(
                        af[mi], bfr[ni], acc[mi][ni], 0, 0, 0);
            }
        if (t + 2 < nt) { asm volatile("s_waitcnt vmcnt(4)" ::: "memory"); }
        else            { asm volatile("s_waitcnt vmcnt(0)" ::: "memory"); }
        __builtin_amdgcn_s_barrier();
        buf ^= 1;
    }

    // ---------------- epilogue ----------------
    if (MODE == M_V) {
        // acc[mi][ni][j]: m = m0+wr+mi*16+g4*4+j (ti), n = n0+wc+ni*16+l15
#pragma unroll
        for (int mi = 0; mi < 4; ++mi) {
            const int mb = m0 + wr + mi * 16 + g4 * 4;
            const int wv_ = mb / 49, ti0 = mb - wv_ * 49;
#pragma unroll
            for (int ni = 0; ni < 4; ++ni) {
                const int n = n0 + wc + ni * 16 + l15;     // h*32+d
                const int h = n >> 5, d = n & 31;
                const float bn = bias[n];
                float v4[4];
#pragma unroll
                for (int j = 0; j < 4; ++j) v4[j] = acc[mi][ni][j] + bn;
                if (ti0 <= 45) {
                    ushort4 u = { bfbits(v4[0]), bfbits(v4[1]), bfbits(v4[2]), bfbits(v4[3]) };
                    *(ushort4*)&((bf16*)Outp)[(((long)wv_ * NHEAD + h) * HD + d) * 64 + ti0] = u;
                } else {
#pragma unroll
                    for (int j = 0; j < 4; ++j) {
                        const int m = mb + j;
                        const int w2 = m / 49, ti = m - w2 * 49;
                        ((bf16*)Outp)[(((long)w2 * NHEAD + h) * HD + d) * 64 + ti]
                            = __float2bfloat16(v4[j]);
                    }
                }
            }
        }
    } else {
        // acc[ni][mi][j]: n = n0+wc+ni*16+g4*4+j, m = m0+wr+mi*16+l15
        long rowbase[4];
        int wq_[4], ti_[4];
#pragma unroll
        for (int mi = 0; mi < 4; ++mi) {
            const int m = m0 + wr + mi * 16 + l15;
            if (MODE == M_QK)       { wq_[mi] = m / 49; ti_[mi] = m - wq_[mi] * 49; }
            else if (MODE == M_FC1) { rowbase[mi] = (long)m * HIDD; }
            else                    { rowbase[mi] = (long)m * CDIM; }
        }
#pragma unroll
        for (int ni = 0; ni < 4; ++ni) {
            const int nb = n0 + wc + ni * 16 + g4 * 4;
            const float4 bn = *(const float4*)&bias[nb];
            const float bb[4] = { bn.x, bn.y, bn.z, bn.w };
#pragma unroll
            for (int mi = 0; mi < 4; ++mi) {
                float v4[4];
#pragma unroll
                for (int j = 0; j < 4; ++j) v4[j] = acc[ni][mi][j] + bb[j];
                if (MODE == M_FC1) {
#pragma unroll
                    for (int j = 0; j < 4; ++j)
                        v4[j] = 0.5f * v4[j] * (1.0f + erff(v4[j] * 0.70710678118654752f));
                } else if (MODE == M_QK) {
                    if (nb < CDIM) {
#pragma unroll
                        for (int j = 0; j < 4; ++j) v4[j] *= QSCALE;
                    }
                }
                ushort4 u = { bfbits(v4[0]), bfbits(v4[1]), bfbits(v4[2]), bfbits(v4[3]) };
                if (MODE == M_QK) {
                    const int which = nb >= CDIM;
                    const int hb = (nb - which * CDIM) >> 5, d0 = nb & 31;
                    *(ushort4*)&((bf16*)Outp)[
                        ((((long)wq_[mi] * 2 + which) * NHEAD + hb) * NTOK + ti_[mi]) * HD + d0] = u;
                } else {
                    *(ushort4*)&((bf16*)Outp)[rowbase[mi] + nb] = u;
                }
            }
        }
    }
}

// ---------------------------------------------------------------------------
// MFMA attention: 4 waves/block, each wave = one (window, head). Unchanged.
// ---------------------------------------------------------------------------
__global__ __launch_bounds__(256)
void mattn_k(const bf16* __restrict__ qk, const bf16* __restrict__ vT,
             const float* __restrict__ tbl, bf16* __restrict__ attn_out)
{
    __shared__ bf16 Plds[4][64 * 72];
    const int tid = threadIdx.x, wid = tid >> 6, lane = tid & 63;
    const int t = blockIdx.x * 4 + wid;
    const int w = t / NHEAD, h = t % NHEAD, wi = w & 63;
    const int l15 = lane & 15, g = lane >> 4;
    const bf16* qb = qk + ((long)(w * 2 + 0) * NHEAD + h) * (NTOK * HD);
    const bf16* kb = qk + ((long)(w * 2 + 1) * NHEAD + h) * (NTOK * HD);
    const bf16* vt = vT + ((long)w * NHEAD + h) * (HD * 64);
    const float* Tb = tbl + (long)(wi * NHEAD + h) * 64 * 64;
    char* Pw = (char*)&Plds[wid][0];

    bf16x8 kf[4], qf[4];
#pragma unroll
    for (int i = 0; i < 4; ++i) {
        kf[i] = *(const bf16x8*)&kb[(16 * i + l15) * HD + 8 * g];
        qf[i] = *(const bf16x8*)&qb[(16 * i + l15) * HD + 8 * g];
    }
    f32x4 s[4][4] = {};
#pragma unroll
    for (int mi = 0; mi < 4; ++mi)
#pragma unroll
        for (int ni = 0; ni < 4; ++ni)
            s[mi][ni] = __builtin_amdgcn_mfma_f32_16x16x32_bf16(
                kf[mi], qf[ni], s[mi][ni], 0, 0, 0);

#pragma unroll
    for (int ni = 0; ni < 4; ++ni) {
        const int n = 16 * ni + l15;
#pragma unroll
        for (int mi = 0; mi < 4; ++mi) {
            float4 tv = *(const float4*)&Tb[(long)n * 64 + 16 * mi + 4 * g];
            s[mi][ni][0] += tv.x; s[mi][ni][1] += tv.y;
            s[mi][ni][2] += tv.z; s[mi][ni][3] += tv.w;
        }
        float mx = NEGBIG;
#pragma unroll
        for (int mi = 0; mi < 4; ++mi)
#pragma unroll
            for (int j = 0; j < 4; ++j) mx = fmaxf(mx, s[mi][ni][j]);
        mx = fmaxf(mx, __shfl_xor(mx, 16));
        mx = fmaxf(mx, __shfl_xor(mx, 32));
        float sum = 0.f;
#pragma unroll
        for (int mi = 0; mi < 4; ++mi)
#pragma unroll
            for (int j = 0; j < 4; ++j) {
                float e = expf(s[mi][ni][j] - mx);
                s[mi][ni][j] = e; sum += e;
            }
        sum += __shfl_xor(sum, 16);
        sum += __shfl_xor(sum, 32);
        const float r = 1.0f / sum;
#pragma unroll
        for (int mi = 0; mi < 4; ++mi) {
            ushort4 u;
            u.x = bfbits(s[mi][ni][0] * r);
            u.y = bfbits(s[mi][ni][1] * r);
            u.z = bfbits(s[mi][ni][2] * r);
            u.w = bfbits(s[mi][ni][3] * r);
            *(ushort4*)(Pw + (long)n * 144 + (16 * mi + 4 * g) * 2) = u;
        }
    }

    f32x4 o[4][2] = {};
#pragma unroll
    for (int kk = 0; kk < 2; ++kk) {
        bf16x8 vf[2];
        vf[0] = *(const bf16x8*)&vt[(long)(l15) * 64 + 32 * kk + 8 * g];
        vf[1] = *(const bf16x8*)&vt[(long)(16 + l15) * 64 + 32 * kk + 8 * g];
#pragma unroll
        for (int rt = 0; rt < 4; ++rt) {
            bf16x8 pf = *(const bf16x8*)(Pw + (long)(16 * rt + l15) * 144 + (32 * kk + 8 * g) * 2);
            o[rt][0] = __builtin_amdgcn_mfma_f32_16x16x32_bf16(pf, vf[0], o[rt][0], 0, 0, 0);
            o[rt][1] = __builtin_amdgcn_mfma_f32_16x16x32_bf16(pf, vf[1], o[rt][1], 0, 0, 0);
        }
    }

#pragma unroll
    for (int rt = 0; rt < 4; ++rt)
#pragma unroll
        for (int dt = 0; dt < 2; ++dt)
#pragma unroll
            for (int j = 0; j < 4; ++j) {
                int n = 16 * rt + 4 * g + j;
                if (n < NTOK)
                    attn_out[((long)w * NTOK + n) * CDIM + h * HD + 16 * dt + l15]
                        = __float2bfloat16(o[rt][dt][j]);
            }
}

// ---------------------------------------------------------------------------
// LN1 streaming: row rl (window order, half-local). tok = reverse-scatter(m).
// x1b[tok_l] = xw[rl](bf16 residual) + LN(P[rl])*g + b   (bf16 out only)
// ---------------------------------------------------------------------------
__global__ __launch_bounds__(256)
void ln1_k(const bf16* __restrict__ P, const bf16* __restrict__ xw,
           const float* __restrict__ g, const float* __restrict__ bta,
           bf16* __restrict__ x1b, int mbase)
{
    const int wv = threadIdx.x >> 6, lane = threadIdx.x & 63;
    const long rl = (long)blockIdx.x * 4 + wv;
    const bool act = lane < 48;
    float vals[8];
    float s = 0.f, sq = 0.f;
    if (act) {
        bf16x8 pv = *(const bf16x8*)&P[rl * CDIM + lane * 8];
#pragma unroll
        for (int j = 0; j < 8; ++j) { vals[j] = (float)pv[j]; s += vals[j]; sq += vals[j] * vals[j]; }
    } else {
#pragma unroll
        for (int j = 0; j < 8; ++j) vals[j] = 0.f;
    }
#pragma unroll
    for (int o = 32; o; o >>= 1) { s += __shfl_xor(s, o); sq += __shfl_xor(sq, o); }
    const float mean = s * (1.f / 384.f);
    const float rstd = rsqrtf(sq * (1.f / 384.f) - mean * mean + EPSLN);

    const int m = mbase + (int)rl;
    int w = m / 49, ti = m - w * 49;
    int b = w >> 6, wi = w & 63;
    int hy = (wi >> 3) * 7 + ti / 7;
    int hx = (wi & 7) * 7 + ti % 7;
    int dh = hy + SSH; if (dh >= HH) dh -= HH;
    int dw = hx + SSH; if (dw >= WW) dw -= WW;
    const long tok_l = (long)b * LTOT + dh * WW + dw - mbase;   // half-local token

    if (act) {
        bf16x8 xv = *(const bf16x8*)&xw[rl * CDIM + lane * 8];
        const int c = lane * 8;
        const float4 g0 = *(const float4*)&g[c],   g1 = *(const float4*)&g[c + 4];
        const float4 b0 = *(const float4*)&bta[c], b1 = *(const float4*)&bta[c + 4];
        const float gg[8] = { g0.x, g0.y, g0.z, g0.w, g1.x, g1.y, g1.z, g1.w };
        const float bb[8] = { b0.x, b0.y, b0.z, b0.w, b1.x, b1.y, b1.z, b1.w };
        ushort4 u0, u1;
        float r0 = (float)xv[0] + (vals[0] - mean) * rstd * gg[0] + bb[0];
        float r1 = (float)xv[1] + (vals[1] - mean) * rstd * gg[1] + bb[1];
        float r2 = (float)xv[2] + (vals[2] - mean) * rstd * gg[2] + bb[2];
        float r3 = (float)xv[3] + (vals[3] - mean) * rstd * gg[3] + bb[3];
        u0 = { bfbits(r0), bfbits(r1), bfbits(r2), bfbits(r3) };
        r0 = (float)xv[4] + (vals[4] - mean) * rstd * gg[4] + bb[4];
        r1 = (float)xv[5] + (vals[5] - mean) * rstd * gg[5] + bb[5];
        r2 = (float)xv[6] + (vals[6] - mean) * rstd * gg[6] + bb[6];
        r3 = (float)xv[7] + (vals[7] - mean) * rstd * gg[7] + bb[7];
        u1 = { bfbits(r0), bfbits(r1), bfbits(r2), bfbits(r3) };
        *(ushort4*)&x1b[tok_l * CDIM + c] = u0;
        *(ushort4*)&x1b[tok_l * CDIM + c + 4] = u1;
    }
}

// ---------------------------------------------------------------------------
// LN2 streaming: out[m] = x1b[rl] + LN(y[rl])*g + b   (fp32 out, token order)
// ---------------------------------------------------------------------------
__global__ __launch_bounds__(256)
void ln2_k(const bf16* __restrict__ y, const bf16* __restrict__ x1b,
           const float* __restrict__ g, const float* __restrict__ bta,
           float* __restrict__ outp, int mbase)
{
    const int wv = threadIdx.x >> 6, lane = threadIdx.x & 63;
    const long rl = (long)blockIdx.x * 4 + wv;
    const bool act = lane < 48;
    float vals[8];
    float s = 0.f, sq = 0.f;
    if (act) {
        bf16x8 yv = *(const bf16x8*)&y[rl * CDIM + lane * 8];
#pragma unroll
        for (int j = 0; j < 8; ++j) { vals[j] = (float)yv[j]; s += vals[j]; sq += vals[j] * vals[j]; }
    } else {
#pragma unroll
        for (int j = 0; j < 8; ++j) vals[j] = 0.f;
    }
#pragma unroll
    for (int o = 32; o; o >>= 1) { s += __shfl_xor(s, o); sq += __shfl_xor(sq, o); }
    const float mean = s * (1.f / 384.f);
    const float rstd = rsqrtf(sq * (1.f / 384.f) - mean * mean + EPSLN);

    if (act) {
        bf16x8 xv = *(const bf16x8*)&x1b[rl * CDIM + lane * 8];
        const int c = lane * 8;
        const float4 g0 = *(const float4*)&g[c],   g1 = *(const float4*)&g[c + 4];
        const float4 b0 = *(const float4*)&bta[c], b1 = *(const float4*)&bta[c + 4];
        float4 o0, o1;
        o0.x = (float)xv[0] + (vals[0] - mean) * rstd * g0.x + b0.x;
        o0.y = (float)xv[1] + (vals[1] - mean) * rstd * g0.y + b0.y;
        o0.z = (float)xv[2] + (vals[2] - mean) * rstd * g0.z + b0.z;
        o0.w = (float)xv[3] + (vals[3] - mean) * rstd * g0.w + b0.w;
        o1.x = (float)xv[4] + (vals[4] - mean) * rstd * g1.x + b1.x;
        o1.y = (float)xv[5] + (vals[5] - mean) * rstd * g1.y + b1.y;
        o1.z = (float)xv[6] + (vals[6] - mean) * rstd * g1.z + b1.z;
        o1.w = (float)xv[7] + (vals[7] - mean) * rstd * g1.w + b1.w;
        const long mg = (long)mbase + rl;
        *(float4*)&outp[mg * CDIM + c] = o0;
        *(float4*)&outp[mg * CDIM + c + 4] = o1;
    }
}

extern "C" void kernel_launch(void* const* d_in, const int* in_sizes, int n_in,
                              void* d_out, int out_size, void* d_ws, size_t ws_size,
                              hipStream_t stream)
{
    const float* x      = (const float*)d_in[0];
    const float* qkv_w  = (const float*)d_in[1];
    const float* qkv_b  = (const float*)d_in[2];
    const float* proj_w = (const float*)d_in[3];
    const float* proj_b = (const float*)d_in[4];
    const float* rpb    = (const float*)d_in[5];
    const float* ln1_g  = (const float*)d_in[6];
    const float* ln1_b  = (const float*)d_in[7];
    const float* fc1_w  = (const float*)d_in[8];
    const float* fc1_b  = (const float*)d_in[9];
    const float* fc2_w  = (const float*)d_in[10];
    const float* fc2_b  = (const float*)d_in[11];
    const float* ln2_g  = (const float*)d_in[12];
    const float* ln2_b  = (const float*)d_in[13];
    const float* amask  = (const float*)d_in[14];
    const int*   relidx = (const int*)d_in[15];
    float* out = (float*)d_out;
    char*  ws  = (char*)d_ws;

    // workspace layout (half-pipelined; peak 297,664,512 B)
    bf16*  wq    = (bf16*) (ws + 0L);            //   884,736
    bf16*  wp    = (bf16*) (ws + 884736L);       //   294,912
    bf16*  w1    = (bf16*) (ws + 1179648L);      // 1,179,648
    bf16*  w2    = (bf16*) (ws + 2359296L);      // 1,179,648
    float* tbl   = (float*)(ws + 3538944L);      // 12,582,912
    bf16*  xw_h  = (bf16*) (ws + 16121856L);     // 38,535,168 (live until ln1)
    bf16*  qkb_h = (bf16*) (ws + 54657024L);     // 77,070,336 (dead after mattn)
    bf16*  vT_h  = (bf16*) (ws + 131727360L);    // 50,331,648 (dead after mattn)
    bf16*  att_h = (bf16*) (ws + 182059008L);    // 38,535,168 (dead after PROJ)
    bf16*  P_h   = (bf16*) (ws + 220594176L);    // 38,535,168 (dead after ln1)
    bf16*  x1b_h = (bf16*) (ws + 259129344L);    // 38,535,168 (live until ln2)
    bf16*  H1_h  = (bf16*) (ws + 16121856L);     // 154,140,672 (reuses xw..vT, FFN)
    bf16*  y_h   = (bf16*) (ws + 170262528L);    // 38,535,168 (reuses vT tail/att)

    dim3 b256(256);

    cvt_k<<<dim3((3*CDIM*CDIM + 255)/256), b256, 0, stream>>>(qkv_w, wq, 3*CDIM*CDIM);
    cvt_k<<<dim3((CDIM*CDIM + 255)/256), b256, 0, stream>>>(proj_w, wp, CDIM*CDIM);
    cvt_k<<<dim3((HIDD*CDIM + 255)/256), b256, 0, stream>>>(fc1_w, w1, HIDD*CDIM);
    cvt_k<<<dim3((CDIM*HIDD + 255)/256), b256, 0, stream>>>(fc2_w, w2, CDIM*HIDD);
    tbl_k<<<dim3(64*12*64*64/256), b256, 0, stream>>>(rpb, relidx, amask, tbl);

    for (int c = 0; c < 2; ++c) {
        const int mb = c * MHALF;
        // 0. shift+window gather (half)
        gather_k<<<dim3(MHALF * 96 / 256), b256, 0, stream>>>(x, xw_h, mb);
        // 1a. Q,K projection   grid = 392*6
        mgemm_k<M_QK, CDIM, 6><<<dim3((MHALF/128)*6), b256, 0, stream>>>(
            xw_h, wq, qkv_b, (void*)qkb_h);
        // 1b. V projection -> [w][h][d][64]  grid = 392*3
        mgemm_k<M_V, CDIM, 3><<<dim3((MHALF/128)*3), b256, 0, stream>>>(
            xw_h, wq + (long)2*CDIM*CDIM, qkv_b + 2*CDIM, (void*)vT_h);
        // 2. attention (1024 windows x 12 heads)
        mattn_k<<<dim3(1024 * NHEAD / 4), b256, 0, stream>>>(qkb_h, vT_h, tbl, att_h);
        // 3. output projection -> P (window-row order, linear)
        mgemm_k<M_ROW, CDIM, 3><<<dim3((MHALF/128)*3), b256, 0, stream>>>(
            att_h, wp, proj_b, (void*)P_h);
        // 4. LN1 + residual (bf16 base xw) + window-reverse scatter -> x1b
        ln1_k<<<dim3(MHALF/4), b256, 0, stream>>>(P_h, xw_h, ln1_g, ln1_b, x1b_h, mb);
        // 5. FC1 + gelu -> H1
        mgemm_k<M_FC1, CDIM, 12><<<dim3((MHALF/128)*12), b256, 0, stream>>>(
            x1b_h, w1, fc1_b, (void*)H1_h);
        // 6. FC2 -> y
        mgemm_k<M_ROW, HIDD, 3><<<dim3((MHALF/128)*3), b256, 0, stream>>>(
            H1_h, w2, fc2_b, (void*)y_h);
        // 7. LN2 + residual -> out fp32
        ln2_k<<<dim3(MHALF/4), b256, 0, stream>>>(y_h, x1b_h, ln2_g, ln2_b, out, mb);
    }
}

// Round 10
// 888.421 us; speedup vs baseline: 1.8408x; 1.0626x over previous
//
#include <hip/hip_runtime.h>
#include <hip/hip_bf16.h>
#include <math.h>

typedef __hip_bfloat16 bf16;
typedef __bf16 bf16x8 __attribute__((ext_vector_type(8)));
typedef float f32x4 __attribute__((ext_vector_type(4)));

#define HH 56
#define WW 56
#define WSZ 7
#define SSH 3
#define NHEAD 12
#define CDIM 384
#define BBATCH 32
#define NTOK 49
#define NWIN 64
#define HIDD 1536
#define HD 32
#define NWTOT (BBATCH*NWIN)
#define MROWS (NWTOT*NTOK)        /* 100352 */
#define MHALF (MROWS/2)           /* 50176 */
#define LTOT (HH*WW)
#define EPSLN 1e-5f
#define QSCALE 0.17677669529663687f
#define NEGBIG -1e30f

enum { M_QK = 0, M_V = 1, M_FC1 = 2 };

__device__ __forceinline__ void gload16(const void* g, void* l) {
    __builtin_amdgcn_global_load_lds(
        (const __attribute__((address_space(1))) void*)g,
        (__attribute__((address_space(3))) void*)l, 16, 0, 0);
}

__device__ __forceinline__ unsigned short bfbits(float v) {
    bf16 b = __float2bfloat16(v);
    return *reinterpret_cast<unsigned short*>(&b);
}

__device__ __forceinline__ float fast_gelu(float v) {
    // tanh-form GELU, overflow-safe; |err vs erf-GELU| <= ~1e-3
    return v / (1.0f + __expf(-1.59576912f * v * fmaf(0.044715f, v * v, 1.0f)));
}

__device__ __forceinline__ int xcd_swz(int orig, int nwg) {
    const int q = nwg >> 3, r = nwg & 7;
    const int xcd = orig & 7, loc = orig >> 3;
    return (xcd < r ? xcd * (q + 1) : r * (q + 1) + (xcd - r) * q) + loc;
}

// ---------------------------------------------------------------------------
__global__ __launch_bounds__(256) void cvt_k(const float* __restrict__ src,
                                             bf16* __restrict__ dst, int n) {
    int i = blockIdx.x * 256 + threadIdx.x;
    if (i < n) dst[i] = __float2bfloat16(src[i]);
}

// bias+mask table: tbl[wi][h][n][m(pad64)] ; m>=49 -> -1e30 (softmax automask)
__global__ __launch_bounds__(256)
void tbl_k(const float* __restrict__ rpb, const int* __restrict__ relidx,
           const float* __restrict__ amask, float* __restrict__ tbl) {
    int idx = blockIdx.x * 256 + threadIdx.x;
    int m = idx & 63, n = (idx >> 6) & 63;
    int h = (idx >> 12) % NHEAD, wi = idx / (64 * 64 * NHEAD);
    float v;
    if (m >= NTOK) v = NEGBIG;
    else if (n >= NTOK) v = 0.f;
    else v = rpb[relidx[n * NTOK + m] * NHEAD + h] + amask[((long)wi * NTOK + n) * NTOK + m];
    tbl[idx] = v;
}

// x fp32 -> xw_h [MHALF][C] bf16, cyclic shift + window partition
__global__ __launch_bounds__(256) void gather_k(const float* __restrict__ x,
                                                bf16* __restrict__ xw, int rbase) {
    int idx = blockIdx.x * 256 + threadIdx.x;
    int rr_l = idx / 96, c4 = (idx % 96) * 4;
    int rr = rbase + rr_l;
    int w = rr / 49, ti = rr % 49;
    int b = w >> 6, wi = w & 63;
    int hy = (wi >> 3) * 7 + ti / 7;
    int hx = (wi & 7) * 7 + ti % 7;
    int sh = hy + SSH; if (sh >= HH) sh -= HH;
    int sw = hx + SSH; if (sw >= WW) sw -= WW;
    float4 v = *(const float4*)&x[((long)b * LTOT + sh * WW + sw) * CDIM + c4];
    ushort4 u = { bfbits(v.x), bfbits(v.y), bfbits(v.z), bfbits(v.w) };
    *(ushort4*)&xw[(long)rr_l * CDIM + c4] = u;
}

// ---------------------------------------------------------------------------
// MFMA GEMM. 128x128 tile, BK=32, 4 waves, LDS 32 KB, 4 blk/CU,
// counted-vmcnt pipeline, T2 swizzle (R9-verified). SWAP except M_V.
// ---------------------------------------------------------------------------
template<int MODE, int KDIM, int NTN>
__global__ __launch_bounds__(256, 4)
void mgemm_k(const bf16* __restrict__ A, const bf16* __restrict__ Wt,
             const float* __restrict__ bias, void* __restrict__ Outp)
{
    constexpr bool SWAP = (MODE != M_V);
    __shared__ bf16 As[2][128 * 32];
    __shared__ bf16 Bs[2][128 * 32];
    const int tid = threadIdx.x;
    const int wid = tid >> 6, lane = tid & 63;

    const int gid = xcd_swz(blockIdx.x, gridDim.x);
    const int m0 = (gid / NTN) * 128;
    const int n0 = (gid % NTN) * 128;

    const int strow = lane >> 2, stseg = lane & 3;
    const int swseg = stseg ^ ((strow >> 1) & 3);
    const bf16* Ag = A + (long)(m0 + wid * 32 + strow) * KDIM + swseg * 8;
    const bf16* Wg = Wt + (long)(n0 + wid * 32 + strow) * KDIM + swseg * 8;

    const int wr = (wid >> 1) * 64, wc = (wid & 1) * 64;
    const int l15 = lane & 15, g4 = lane >> 4;
    const int sa = g4 ^ ((l15 >> 1) & 3);

    f32x4 acc[4][4] = {};

    auto STAGE = [&](int b, int t) {
#pragma unroll
        for (int i = 0; i < 2; ++i)
            gload16(Ag + (long)(i * 16) * KDIM + t * 32, &As[b][(wid * 32 + i * 16) * 32]);
#pragma unroll
        for (int i = 0; i < 2; ++i)
            gload16(Wg + (long)(i * 16) * KDIM + t * 32, &Bs[b][(wid * 32 + i * 16) * 32]);
    };

    const int nt = KDIM / 32;
    STAGE(0, 0);
    STAGE(1, 1);
    asm volatile("s_waitcnt vmcnt(4)" ::: "memory");
    __builtin_amdgcn_s_barrier();

    int buf = 0;
    for (int t = 0; t < nt; ++t) {
        bf16x8 af[4], bfr[4];
#pragma unroll
        for (int i = 0; i < 4; ++i) {
            af[i]  = *(const bf16x8*)&As[buf][(wr + i * 16 + l15) * 32 + sa * 8];
            bfr[i] = *(const bf16x8*)&Bs[buf][(wc + i * 16 + l15) * 32 + sa * 8];
        }
        __builtin_amdgcn_sched_barrier(0);
        asm volatile("s_waitcnt lgkmcnt(0)" ::: "memory");
        __builtin_amdgcn_sched_barrier(0);
        __builtin_amdgcn_s_barrier();
        if (t + 2 < nt) STAGE(buf, t + 2);
#pragma unroll
        for (int mi = 0; mi < 4; ++mi)
#pragma unroll
            for (int ni = 0; ni < 4; ++ni) {
                if (SWAP)
                    acc[ni][mi] = __builtin_amdgcn_mfma_f32_16x16x32_bf16(
                        bfr[ni], af[mi], acc[ni][mi], 0, 0, 0);
                else
                    acc[mi][ni] = __builtin_amdgcn_mfma_f32_16x16x32_bf16(
                        af[mi], bfr[ni], acc[mi][ni], 0, 0, 0);
            }
        if (t + 2 < nt) { asm volatile("s_waitcnt vmcnt(4)" ::: "memory"); }
        else            { asm volatile("s_waitcnt vmcnt(0)" ::: "memory"); }
        __builtin_amdgcn_s_barrier();
        buf ^= 1;
    }

    if (MODE == M_V) {
#pragma unroll
        for (int mi = 0; mi < 4; ++mi) {
            const int mb = m0 + wr + mi * 16 + g4 * 4;
            const int wv_ = mb / 49, ti0 = mb - wv_ * 49;
#pragma unroll
            for (int ni = 0; ni < 4; ++ni) {
                const int n = n0 + wc + ni * 16 + l15;
                const int h = n >> 5, d = n & 31;
                const float bn = bias[n];
                float v4[4];
#pragma unroll
                for (int j = 0; j < 4; ++j) v4[j] = acc[mi][ni][j] + bn;
                if (ti0 <= 45) {
                    ushort4 u = { bfbits(v4[0]), bfbits(v4[1]), bfbits(v4[2]), bfbits(v4[3]) };
                    *(ushort4*)&((bf16*)Outp)[(((long)wv_ * NHEAD + h) * HD + d) * 64 + ti0] = u;
                } else {
#pragma unroll
                    for (int j = 0; j < 4; ++j) {
                        const int m = mb + j;
                        const int w2 = m / 49, ti = m - w2 * 49;
                        ((bf16*)Outp)[(((long)w2 * NHEAD + h) * HD + d) * 64 + ti]
                            = __float2bfloat16(v4[j]);
                    }
                }
            }
        }
    } else {
        long rowbase[4];
        int wq_[4], ti_[4];
#pragma unroll
        for (int mi = 0; mi < 4; ++mi) {
            const int m = m0 + wr + mi * 16 + l15;
            if (MODE == M_QK) { wq_[mi] = m / 49; ti_[mi] = m - wq_[mi] * 49; }
            else              { rowbase[mi] = (long)m * HIDD; }
        }
#pragma unroll
        for (int ni = 0; ni < 4; ++ni) {
            const int nb = n0 + wc + ni * 16 + g4 * 4;
            const float4 bn = *(const float4*)&bias[nb];
            const float bb[4] = { bn.x, bn.y, bn.z, bn.w };
#pragma unroll
            for (int mi = 0; mi < 4; ++mi) {
                float v4[4];
#pragma unroll
                for (int j = 0; j < 4; ++j) v4[j] = acc[ni][mi][j] + bb[j];
                if (MODE == M_FC1) {
#pragma unroll
                    for (int j = 0; j < 4; ++j) v4[j] = fast_gelu(v4[j]);
                } else if (MODE == M_QK) {
                    if (nb < CDIM) {
#pragma unroll
                        for (int j = 0; j < 4; ++j) v4[j] *= QSCALE;
                    }
                }
                ushort4 u = { bfbits(v4[0]), bfbits(v4[1]), bfbits(v4[2]), bfbits(v4[3]) };
                if (MODE == M_QK) {
                    const int which = nb >= CDIM;
                    const int hb = (nb - which * CDIM) >> 5, d0 = nb & 31;
                    *(ushort4*)&((bf16*)Outp)[
                        ((((long)wq_[mi] * 2 + which) * NHEAD + hb) * NTOK + ti_[mi]) * HD + d0] = u;
                } else {
                    *(ushort4*)&((bf16*)Outp)[rowbase[mi] + nb] = u;
                }
            }
        }
    }
}

// ---------------------------------------------------------------------------
// Fused GEMM(64 x 384 x K) + row-LayerNorm + residual.
// 256 thr = 4 waves (1M x 4N), wave = 64 rows x 96 cols (acc[6][4] f32x4).
// A dbuf 8 KB + B dbuf 48 KB + lnp 2 KB -> 2 blk/CU; counted-vmcnt pipeline
// (7 uniform loads/thread/stage -> vmcnt(7)); T2 swizzle.
// SCATTER=1 (PROJ+LN1): resid = xw (window-row order), scatter-write bf16 x1b.
// SCATTER=0 (FC2+LN2):  resid = x1b (token order), write fp32 out.
// ---------------------------------------------------------------------------
template<int KDIM, bool SCATTER>
__global__ __launch_bounds__(256, 2)
void gemm_ln_k(const bf16* __restrict__ A, const bf16* __restrict__ Wt,
               const float* __restrict__ bias, const bf16* __restrict__ resid,
               const float* __restrict__ lng, const float* __restrict__ lnb,
               float* __restrict__ outf, bf16* __restrict__ outb, int mbase)
{
    __shared__ bf16 As[2][64 * 32];      // 8 KB
    __shared__ bf16 Bs[2][384 * 32];     // 48 KB
    __shared__ float lnp[512];           // 2 KB: [sum|sq][4 waves][64 rows]
    const int tid = threadIdx.x;
    const int wid = tid >> 6, lane = tid & 63;

    const int m0 = xcd_swz(blockIdx.x, gridDim.x) * 64;

    const int strow = tid >> 2, stseg = tid & 3;           // 64 rows x 4 segs
    const int swr = stseg ^ ((strow >> 1) & 3);
    const bf16* Ag = A + (long)(m0 + strow) * KDIM + swr * 8;
    const bf16* Wg = Wt + (long)strow * KDIM + swr * 8;

    const int wc = wid * 96;
    const int l15 = lane & 15, g4 = lane >> 4;
    const int sa = g4 ^ ((l15 >> 1) & 3);

    f32x4 acc[6][4] = {};   // [ni][mi]: n = wc+ni*16+g4*4+j, m = mi*16+l15

    auto STAGE = [&](int b, int t) {
        gload16(Ag + t * 32, &As[b][strow * 32 + stseg * 8]);
#pragma unroll
        for (int i = 0; i < 6; ++i)
            gload16(Wg + (long)(i * 64) * KDIM + t * 32,
                    &Bs[b][(strow + i * 64) * 32 + stseg * 8]);
    };

    const int nt = KDIM / 32;
    STAGE(0, 0);
    STAGE(1, 1);
    asm volatile("s_waitcnt vmcnt(7)" ::: "memory");
    __builtin_amdgcn_s_barrier();

    int buf = 0;
    for (int t = 0; t < nt; ++t) {
        bf16x8 af[4], bfr[6];
#pragma unroll
        for (int i = 0; i < 4; ++i)
            af[i] = *(const bf16x8*)&As[buf][(i * 16 + l15) * 32 + sa * 8];
#pragma unroll
        for (int i = 0; i < 6; ++i)
            bfr[i] = *(const bf16x8*)&Bs[buf][(wc + i * 16 + l15) * 32 + sa * 8];
        __builtin_amdgcn_sched_barrier(0);
        asm volatile("s_waitcnt lgkmcnt(0)" ::: "memory");
        __builtin_amdgcn_sched_barrier(0);
        __builtin_amdgcn_s_barrier();
        if (t + 2 < nt) STAGE(buf, t + 2);
#pragma unroll
        for (int ni = 0; ni < 6; ++ni)
#pragma unroll
            for (int mi = 0; mi < 4; ++mi)
                acc[ni][mi] = __builtin_amdgcn_mfma_f32_16x16x32_bf16(
                    bfr[ni], af[mi], acc[ni][mi], 0, 0, 0);
        if (t + 2 < nt) { asm volatile("s_waitcnt vmcnt(7)" ::: "memory"); }
        else            { asm volatile("s_waitcnt vmcnt(0)" ::: "memory"); }
        __builtin_amdgcn_s_barrier();
        buf ^= 1;
    }

    // ---- bias add + per-row partial sums (this wave's 96 cols) ----
    float psum[4] = {}, psq[4] = {};
#pragma unroll
    for (int ni = 0; ni < 6; ++ni) {
        const int nb = wc + ni * 16 + g4 * 4;
        const float4 bn = *(const float4*)&bias[nb];
        const float bb[4] = { bn.x, bn.y, bn.z, bn.w };
#pragma unroll
        for (int mi = 0; mi < 4; ++mi)
#pragma unroll
            for (int j = 0; j < 4; ++j) {
                float v = acc[ni][mi][j] + bb[j];
                acc[ni][mi][j] = v;
                psum[mi] += v; psq[mi] += v * v;
            }
    }
#pragma unroll
    for (int mi = 0; mi < 4; ++mi) {
        psum[mi] += __shfl_xor(psum[mi], 16); psum[mi] += __shfl_xor(psum[mi], 32);
        psq[mi]  += __shfl_xor(psq[mi], 16);  psq[mi]  += __shfl_xor(psq[mi], 32);
    }
    if (g4 == 0) {
#pragma unroll
        for (int mi = 0; mi < 4; ++mi) {
            const int r = mi * 16 + l15;
            lnp[wid * 64 + r] = psum[mi];
            lnp[256 + wid * 64 + r] = psq[mi];
        }
    }
    __syncthreads();

#pragma unroll
    for (int mi = 0; mi < 4; ++mi) {
        const int r = mi * 16 + l15;
        const float s  = lnp[r] + lnp[64 + r] + lnp[128 + r] + lnp[192 + r];
        const float sq = lnp[256 + r] + lnp[320 + r] + lnp[384 + r] + lnp[448 + r];
        const float mean = s * (1.f / 384.f);
        const float rstd = rsqrtf(sq * (1.f / 384.f) - mean * mean + EPSLN);

        const long rl = m0 + r;              // half-local row (window or token order)
        long dst;
        if (SCATTER) {
            const int m = mbase + (int)rl;   // global window-row -> token scatter
            int w = m / 49, ti = m - w * 49;
            int b = w >> 6, wi = w & 63;
            int hy = (wi >> 3) * 7 + ti / 7;
            int hx = (wi & 7) * 7 + ti % 7;
            int dh = hy + SSH; if (dh >= HH) dh -= HH;
            int dw = hx + SSH; if (dw >= WW) dw -= WW;
            dst = (long)b * LTOT + dh * WW + dw - mbase;   // half-local token
        } else {
            dst = mbase + rl;                // global row for fp32 out
        }
#pragma unroll
        for (int ni = 0; ni < 6; ++ni) {
            const int c = wc + ni * 16 + g4 * 4;
            const float4 gv = *(const float4*)&lng[c];
            const float4 bv = *(const float4*)&lnb[c];
            ushort4 xv = *(const ushort4*)&resid[rl * CDIM + c];
            float x0 = __bfloat162float(*(bf16*)&xv.x);
            float x1 = __bfloat162float(*(bf16*)&xv.y);
            float x2 = __bfloat162float(*(bf16*)&xv.z);
            float x3 = __bfloat162float(*(bf16*)&xv.w);
            float r0 = x0 + (acc[ni][mi][0] - mean) * rstd * gv.x + bv.x;
            float r1 = x1 + (acc[ni][mi][1] - mean) * rstd * gv.y + bv.y;
            float r2 = x2 + (acc[ni][mi][2] - mean) * rstd * gv.z + bv.z;
            float r3 = x3 + (acc[ni][mi][3] - mean) * rstd * gv.w + bv.w;
            if (SCATTER) {
                ushort4 u = { bfbits(r0), bfbits(r1), bfbits(r2), bfbits(r3) };
                *(ushort4*)&outb[dst * CDIM + c] = u;
            } else {
                float4 o = { r0, r1, r2, r3 };
                *(float4*)&outf[dst * CDIM + c] = o;
            }
        }
    }
}

// ---------------------------------------------------------------------------
// MFMA attention: 4 waves/block, each wave = one (window, head). Unchanged.
// ---------------------------------------------------------------------------
__global__ __launch_bounds__(256)
void mattn_k(const bf16* __restrict__ qk, const bf16* __restrict__ vT,
             const float* __restrict__ tbl, bf16* __restrict__ attn_out)
{
    __shared__ bf16 Plds[4][64 * 72];
    const int tid = threadIdx.x, wid = tid >> 6, lane = tid & 63;
    const int t = blockIdx.x * 4 + wid;
    const int w = t / NHEAD, h = t % NHEAD, wi = w & 63;
    const int l15 = lane & 15, g = lane >> 4;
    const bf16* qb = qk + ((long)(w * 2 + 0) * NHEAD + h) * (NTOK * HD);
    const bf16* kb = qk + ((long)(w * 2 + 1) * NHEAD + h) * (NTOK * HD);
    const bf16* vt = vT + ((long)w * NHEAD + h) * (HD * 64);
    const float* Tb = tbl + (long)(wi * NHEAD + h) * 64 * 64;
    char* Pw = (char*)&Plds[wid][0];

    bf16x8 kf[4], qf[4];
#pragma unroll
    for (int i = 0; i < 4; ++i) {
        kf[i] = *(const bf16x8*)&kb[(16 * i + l15) * HD + 8 * g];
        qf[i] = *(const bf16x8*)&qb[(16 * i + l15) * HD + 8 * g];
    }
    f32x4 s[4][4] = {};
#pragma unroll
    for (int mi = 0; mi < 4; ++mi)
#pragma unroll
        for (int ni = 0; ni < 4; ++ni)
            s[mi][ni] = __builtin_amdgcn_mfma_f32_16x16x32_bf16(
                kf[mi], qf[ni], s[mi][ni], 0, 0, 0);

#pragma unroll
    for (int ni = 0; ni < 4; ++ni) {
        const int n = 16 * ni + l15;
#pragma unroll
        for (int mi = 0; mi < 4; ++mi) {
            float4 tv = *(const float4*)&Tb[(long)n * 64 + 16 * mi + 4 * g];
            s[mi][ni][0] += tv.x; s[mi][ni][1] += tv.y;
            s[mi][ni][2] += tv.z; s[mi][ni][3] += tv.w;
        }
        float mx = NEGBIG;
#pragma unroll
        for (int mi = 0; mi < 4; ++mi)
#pragma unroll
            for (int j = 0; j < 4; ++j) mx = fmaxf(mx, s[mi][ni][j]);
        mx = fmaxf(mx, __shfl_xor(mx, 16));
        mx = fmaxf(mx, __shfl_xor(mx, 32));
        float sum = 0.f;
#pragma unroll
        for (int mi = 0; mi < 4; ++mi)
#pragma unroll
            for (int j = 0; j < 4; ++j) {
                float e = expf(s[mi][ni][j] - mx);
                s[mi][ni][j] = e; sum += e;
            }
        sum += __shfl_xor(sum, 16);
        sum += __shfl_xor(sum, 32);
        const float r = 1.0f / sum;
#pragma unroll
        for (int mi = 0; mi < 4; ++mi) {
            ushort4 u;
            u.x = bfbits(s[mi][ni][0] * r);
            u.y = bfbits(s[mi][ni][1] * r);
            u.z = bfbits(s[mi][ni][2] * r);
            u.w = bfbits(s[mi][ni][3] * r);
            *(ushort4*)(Pw + (long)n * 144 + (16 * mi + 4 * g) * 2) = u;
        }
    }

    f32x4 o[4][2] = {};
#pragma unroll
    for (int kk = 0; kk < 2; ++kk) {
        bf16x8 vf[2];
        vf[0] = *(const bf16x8*)&vt[(long)(l15) * 64 + 32 * kk + 8 * g];
        vf[1] = *(const bf16x8*)&vt[(long)(16 + l15) * 64 + 32 * kk + 8 * g];
#pragma unroll
        for (int rt = 0; rt < 4; ++rt) {
            bf16x8 pf = *(const bf16x8*)(Pw + (long)(16 * rt + l15) * 144 + (32 * kk + 8 * g) * 2);
            o[rt][0] = __builtin_amdgcn_mfma_f32_16x16x32_bf16(pf, vf[0], o[rt][0], 0, 0, 0);
            o[rt][1] = __builtin_amdgcn_mfma_f32_16x16x32_bf16(pf, vf[1], o[rt][1], 0, 0, 0);
        }
    }

#pragma unroll
    for (int rt = 0; rt < 4; ++rt)
#pragma unroll
        for (int dt = 0; dt < 2; ++dt)
#pragma unroll
            for (int j = 0; j < 4; ++j) {
                int n = 16 * rt + 4 * g + j;
                if (n < NTOK)
                    attn_out[((long)w * NTOK + n) * CDIM + h * HD + 16 * dt + l15]
                        = __float2bfloat16(o[rt][dt][j]);
            }
}

extern "C" void kernel_launch(void* const* d_in, const int* in_sizes, int n_in,
                              void* d_out, int out_size, void* d_ws, size_t ws_size,
                              hipStream_t stream)
{
    const float* x      = (const float*)d_in[0];
    const float* qkv_w  = (const float*)d_in[1];
    const float* qkv_b  = (const float*)d_in[2];
    const float* proj_w = (const float*)d_in[3];
    const float* proj_b = (const float*)d_in[4];
    const float* rpb    = (const float*)d_in[5];
    const float* ln1_g  = (const float*)d_in[6];
    const float* ln1_b  = (const float*)d_in[7];
    const float* fc1_w  = (const float*)d_in[8];
    const float* fc1_b  = (const float*)d_in[9];
    const float* fc2_w  = (const float*)d_in[10];
    const float* fc2_b  = (const float*)d_in[11];
    const float* ln2_g  = (const float*)d_in[12];
    const float* ln2_b  = (const float*)d_in[13];
    const float* amask  = (const float*)d_in[14];
    const int*   relidx = (const int*)d_in[15];
    float* out = (float*)d_out;
    char*  ws  = (char*)d_ws;

    // workspace layout (half-pipelined; peak 259,129,344 B)
    bf16*  wq    = (bf16*) (ws + 0L);
    bf16*  wp    = (bf16*) (ws + 884736L);
    bf16*  w1    = (bf16*) (ws + 1179648L);
    bf16*  w2    = (bf16*) (ws + 2359296L);
    float* tbl   = (float*)(ws + 3538944L);      // 12,582,912
    bf16*  xw_h  = (bf16*) (ws + 16121856L);     // 38,535,168 (live until proj_ln)
    bf16*  qkb_h = (bf16*) (ws + 54657024L);     // 77,070,336 (dead after mattn)
    bf16*  vT_h  = (bf16*) (ws + 131727360L);    // 50,331,648 (dead after mattn)
    bf16*  att_h = (bf16*) (ws + 182059008L);    // 38,535,168 (dead after proj_ln)
    bf16*  x1b_h = (bf16*) (ws + 220594176L);    // 38,535,168 (live until fc2_ln)
    bf16*  H1_h  = (bf16*) (ws + 16121856L);     // 154,140,672 (reuses xw..vT)

    dim3 b256(256);

    cvt_k<<<dim3((3*CDIM*CDIM + 255)/256), b256, 0, stream>>>(qkv_w, wq, 3*CDIM*CDIM);
    cvt_k<<<dim3((CDIM*CDIM + 255)/256), b256, 0, stream>>>(proj_w, wp, CDIM*CDIM);
    cvt_k<<<dim3((HIDD*CDIM + 255)/256), b256, 0, stream>>>(fc1_w, w1, HIDD*CDIM);
    cvt_k<<<dim3((CDIM*HIDD + 255)/256), b256, 0, stream>>>(fc2_w, w2, CDIM*HIDD);
    tbl_k<<<dim3(64*12*64*64/256), b256, 0, stream>>>(rpb, relidx, amask, tbl);

    for (int c = 0; c < 2; ++c) {
        const int mb = c * MHALF;
        // 0. shift+window gather (half)
        gather_k<<<dim3(MHALF * 96 / 256), b256, 0, stream>>>(x, xw_h, mb);
        // 1a. Q,K projection
        mgemm_k<M_QK, CDIM, 6><<<dim3((MHALF/128)*6), b256, 0, stream>>>(
            xw_h, wq, qkv_b, (void*)qkb_h);
        // 1b. V projection -> [w][h][d][64]
        mgemm_k<M_V, CDIM, 3><<<dim3((MHALF/128)*3), b256, 0, stream>>>(
            xw_h, wq + (long)2*CDIM*CDIM, qkv_b + 2*CDIM, (void*)vT_h);
        // 2. attention
        mattn_k<<<dim3(1024 * NHEAD / 4), b256, 0, stream>>>(qkb_h, vT_h, tbl, att_h);
        // 3. PROJ + LN1 + residual(xw) + window-reverse scatter -> x1b (bf16)
        gemm_ln_k<CDIM, true><<<dim3(MHALF/64), b256, 0, stream>>>(
            att_h, wp, proj_b, xw_h, ln1_g, ln1_b, nullptr, x1b_h, mb);
        // 4. FC1 + fast-gelu -> H1
        mgemm_k<M_FC1, CDIM, 12><<<dim3((MHALF/128)*12), b256, 0, stream>>>(
            x1b_h, w1, fc1_b, (void*)H1_h);
        // 5. FC2 + LN2 + residual(x1b) -> out (fp32)
        gemm_ln_k<HIDD, false><<<dim3(MHALF/64), b256, 0, stream>>>(
            H1_h, w2, fc2_b, x1b_h, ln2_g, ln2_b, out, nullptr, mb);
    }
}